// Round 6
// baseline (1313.955 us; speedup 1.0000x reference)
//
#include <hip/hip_runtime.h>
#include <math.h>

// BayesianCTC on MI355X — round 17 (= R16 resubmitted; container infra flake,
// no kernel signal). Audited for hang/OOB: barrier counts loop-uniform
// outside compute guards; all row indices bounded; pad reads by design.
// R16 theory: per-step cost is dominated by ~900cy of per-ROUND-TRIP overhead
// (proven by R11->R14 delta). k=2 STEP FUSION divides it: each thread reads
// 6 contiguous states, recomputes step t's intermediates locally
// (bit-identical), computes step t+1 finals, writes 2, ONE barrier per 2
// steps. Round trips 1600->~800, arith x1.5. lpbk preloaded to LDS ebs[]
// (wave-uniform loads were s_load -> drained by every STEP_BAR lgkmcnt(0)).
// All per-step formulas verbatim R14 (lse ordering, classifier, resets).

#define Bn    16
#define Tn    1600
#define NE    512
#define OD    2048
#define Un    200
#define Sn    401
#define NLAB  201
#define NGC   256

#define NEGINF (-INFINITY)
#define LSE_SUB_CONST_F (-2000.4586715f)        // -2001 + log(e-1)

typedef short bf8_t  __attribute__((ext_vector_type(8)));
typedef float f32x4  __attribute__((ext_vector_type(4)));

__device__ __forceinline__ unsigned short f2bf(float x) {
    unsigned int u = __float_as_uint(x);
    unsigned int r = (u + 0x7FFFu + ((u >> 16) & 1u)) >> 16;  // RNE
    return (unsigned short)r;
}
__device__ __forceinline__ void lse_merge_v(float& M, float& S, float v) {
    if (v > M) { S = S * __expf(M - v) + 1.f; M = v; }
    else       { S += __expf(v - M); }
}
__device__ __forceinline__ void lse_merge_ms(float& M, float& S, float m2, float s2) {
    if (s2 > 0.f) {
        if (m2 > M) { S = S * __expf(M - m2) + s2; M = m2; }
        else        { S += s2 * __expf(m2 - M); }
    }
}

// ------------------------------------------------------------ casts -------
__global__ __launch_bounds__(256)
void cast_hs_kernel(const float* __restrict__ src, unsigned short* __restrict__ dst, int n8) {
    int i = blockIdx.x * 256 + threadIdx.x;
    if (i >= n8) return;
    const float4* s4 = (const float4*)(src + (size_t)i * 8);
    float4 a = s4[0], b = s4[1];
    uint4 o;
    o.x = f2bf(a.x) | ((unsigned)f2bf(a.y) << 16);
    o.y = f2bf(a.z) | ((unsigned)f2bf(a.w) << 16);
    o.z = f2bf(b.x) | ((unsigned)f2bf(b.y) << 16);
    o.w = f2bf(b.z) | ((unsigned)f2bf(b.w) << 16);
    *(uint4*)(dst + (size_t)i * 8) = o;
}

// --------------------------------------------------------- gather Wg ------
__global__ __launch_bounds__(64)
void gather_kernel(const float* __restrict__ W, const float* __restrict__ bias,
                   const int* __restrict__ ys, unsigned short* __restrict__ Wgb,
                   float* __restrict__ biasg)
{
    const int b = blockIdx.x, j = blockIdx.y, tid = threadIdx.x;
    int col = -1;
    if (j == 0) col = 0;
    else if (j <= Un) { int y = ys[b * Un + j - 1]; col = (y < 0) ? 0 : y; }
    unsigned short* dst = Wgb + ((size_t)b * NGC + j) * NE;
    if (col >= 0) {
        const float* srcc = W + (size_t)col * NE;
        #pragma unroll
        for (int it = 0; it < 8; ++it) dst[tid + it * 64] = f2bf(srcc[tid + it * 64]);
    } else {
        #pragma unroll
        for (int it = 0; it < 8; ++it) dst[tid + it * 64] = 0;
    }
    if (tid == 0) biasg[b * NGC + j] = (col >= 0) ? bias[col] : 0.f;
}

// ------------------------------------------------------- main MFMA GEMM ---
#define KCH  64
#define ASTR 72

__global__ __launch_bounds__(256, 2)
void gemm_main_kernel(const unsigned short* __restrict__ hsb,
                      const unsigned short* __restrict__ Wb,
                      const float* __restrict__ bias,
                      float* __restrict__ Pm, float* __restrict__ Ps)
{
    __shared__ union {
        struct { unsigned short A[128 * ASTR]; unsigned short B[128 * ASTR]; } t;
        struct { float m[128 * 33]; float s[128 * 33]; } r;
    } sh;
    const int tid  = threadIdx.x;
    const int lane = tid & 63, w = tid >> 6;
    const int mw = w & 1, nw = w >> 1;
    const int quad = lane >> 4, lc = lane & 15;
    const int row0 = blockIdx.x * 128;
    const int c0   = blockIdx.y * 128;

    f32x4 acc[4][4];
    #pragma unroll
    for (int mi = 0; mi < 4; ++mi)
        #pragma unroll
        for (int ni = 0; ni < 4; ++ni) acc[mi][ni] = (f32x4)0.f;

    for (int kc = 0; kc < NE / KCH; ++kc) {
        __syncthreads();
        #pragma unroll
        for (int i = 0; i < 4; ++i) {
            int idx = tid + i * 256;
            int r = idx >> 3, c8 = idx & 7;
            *(uint4*)&sh.t.A[r * ASTR + c8 * 8] =
                *(const uint4*)&hsb[(size_t)(row0 + r) * NE + kc * KCH + c8 * 8];
            *(uint4*)&sh.t.B[r * ASTR + c8 * 8] =
                *(const uint4*)&Wb[(size_t)(c0 + r) * NE + kc * KCH + c8 * 8];
        }
        __syncthreads();
        #pragma unroll
        for (int ks = 0; ks < 2; ++ks) {
            bf8_t af[4], bg[4];
            #pragma unroll
            for (int mi = 0; mi < 4; ++mi)
                af[mi] = *(const bf8_t*)&sh.t.A[(mw * 64 + mi * 16 + lc) * ASTR + ks * 32 + quad * 8];
            #pragma unroll
            for (int ni = 0; ni < 4; ++ni)
                bg[ni] = *(const bf8_t*)&sh.t.B[(nw * 64 + ni * 16 + lc) * ASTR + ks * 32 + quad * 8];
            #pragma unroll
            for (int mi = 0; mi < 4; ++mi)
                #pragma unroll
                for (int ni = 0; ni < 4; ++ni)
                    acc[mi][ni] = __builtin_amdgcn_mfma_f32_16x16x32_bf16(af[mi], bg[ni], acc[mi][ni], 0, 0, 0);
        }
    }
    __syncthreads();
    float bcol[4];
    #pragma unroll
    for (int ni = 0; ni < 4; ++ni) bcol[ni] = bias[c0 + nw * 64 + ni * 16 + lc];
    #pragma unroll
    for (int mi = 0; mi < 4; ++mi)
        #pragma unroll
        for (int r = 0; r < 4; ++r) {
            float M = NEGINF, S = 0.f;
            #pragma unroll
            for (int ni = 0; ni < 4; ++ni) lse_merge_v(M, S, acc[mi][ni][r] + bcol[ni]);
            int rl = mw * 64 + mi * 16 + quad * 4 + r;
            sh.r.m[rl * 33 + nw * 16 + lc] = M;
            sh.r.s[rl * 33 + nw * 16 + lc] = S;
        }
    __syncthreads();
    if (tid < 128) {
        float M = NEGINF, S = 0.f;
        #pragma unroll 4
        for (int j = 0; j < 32; ++j) lse_merge_ms(M, S, sh.r.m[tid * 33 + j], sh.r.s[tid * 33 + j]);
        Pm[(size_t)blockIdx.y * 25600 + row0 + tid] = M;
        Ps[(size_t)blockIdx.y * 25600 + row0 + tid] = S;
    }
}

// ------------------------------------------------------------ lse reduce --
__global__ __launch_bounds__(256)
void lse_reduce_kernel(const float* __restrict__ Pm, const float* __restrict__ Ps,
                       float* __restrict__ lse)
{
    int row = blockIdx.x * 256 + threadIdx.x;
    float M = NEGINF, S = 0.f;
    #pragma unroll 4
    for (int nt = 0; nt < 16; ++nt)
        lse_merge_ms(M, S, Pm[(size_t)nt * 25600 + row], Ps[(size_t)nt * 25600 + row]);
    lse[row] = M + logf(S);
}

// ------------------------------------------------------- label MFMA GEMM --
// Output split — lpbk[row] = blank col, lpl[row][u] = label col u (u<200).
__global__ __launch_bounds__(256, 2)
void gemm_label_kernel(const unsigned short* __restrict__ hsb,
                       const unsigned short* __restrict__ Wgb,
                       const float* __restrict__ biasg, const float* __restrict__ lse,
                       float* __restrict__ lpl, float* __restrict__ lpbk)
{
    __shared__ unsigned short shA[64 * ASTR];
    __shared__ unsigned short shB[128 * ASTR];
    const int tid  = threadIdx.x;
    const int lane = tid & 63, w = tid >> 6;
    const int mw = w & 1, nw = w >> 1;
    const int quad = lane >> 4, lc = lane & 15;
    const int b  = blockIdx.x / 25, mt = blockIdx.x % 25;
    const int r0 = b * Tn + mt * 64;
    const int c0 = blockIdx.y * 128;

    f32x4 acc[2][4];
    #pragma unroll
    for (int mi = 0; mi < 2; ++mi)
        #pragma unroll
        for (int ni = 0; ni < 4; ++ni) acc[mi][ni] = (f32x4)0.f;

    const unsigned short* Wgbb = Wgb + (size_t)b * NGC * NE;
    for (int kc = 0; kc < NE / KCH; ++kc) {
        __syncthreads();
        #pragma unroll
        for (int i = 0; i < 2; ++i) {
            int idx = tid + i * 256;
            int r = idx >> 3, c8 = idx & 7;
            *(uint4*)&shA[r * ASTR + c8 * 8] =
                *(const uint4*)&hsb[(size_t)(r0 + r) * NE + kc * KCH + c8 * 8];
        }
        #pragma unroll
        for (int i = 0; i < 4; ++i) {
            int idx = tid + i * 256;
            int r = idx >> 3, c8 = idx & 7;
            *(uint4*)&shB[r * ASTR + c8 * 8] =
                *(const uint4*)&Wgbb[(size_t)(c0 + r) * NE + kc * KCH + c8 * 8];
        }
        __syncthreads();
        #pragma unroll
        for (int ks = 0; ks < 2; ++ks) {
            bf8_t af[2], bg[4];
            #pragma unroll
            for (int mi = 0; mi < 2; ++mi)
                af[mi] = *(const bf8_t*)&shA[(mw * 32 + mi * 16 + lc) * ASTR + ks * 32 + quad * 8];
            #pragma unroll
            for (int ni = 0; ni < 4; ++ni)
                bg[ni] = *(const bf8_t*)&shB[(nw * 64 + ni * 16 + lc) * ASTR + ks * 32 + quad * 8];
            #pragma unroll
            for (int mi = 0; mi < 2; ++mi)
                #pragma unroll
                for (int ni = 0; ni < 4; ++ni)
                    acc[mi][ni] = __builtin_amdgcn_mfma_f32_16x16x32_bf16(af[mi], bg[ni], acc[mi][ni], 0, 0, 0);
        }
    }
    #pragma unroll
    for (int mi = 0; mi < 2; ++mi)
        #pragma unroll
        for (int r = 0; r < 4; ++r) {
            int row = r0 + mw * 32 + mi * 16 + quad * 4 + r;
            float lsv = lse[row];
            #pragma unroll
            for (int ni = 0; ni < 4; ++ni) {
                int col = c0 + nw * 64 + ni * 16 + lc;
                if (col < NLAB) {
                    float v = acc[mi][ni][r] + biasg[b * NGC + col] - lsv;
                    if (col == 0) lpbk[row] = v;
                    else          lpl[(size_t)row * Un + (col - 1)] = v;
                }
            }
        }
}

// ------------------- K2: LDS ping-pong scan, k=2 fused --------------------
// IDX(s) = s + 4: pads cover states -4..-1 (alpha stencil) and 401..407
// (beta stencil); pads are never written, stay NEGINF.
#define IDX(s) ((s) + 4)

__device__ __forceinline__ float lse2f(float a, float b) {
    float mx = fmaxf(a, b);
    if (isinf(mx)) return NEGINF;
    return mx + __logf(__expf(a - mx) + __expf(b - mx));
}
__device__ __forceinline__ float lse3f(float v0, float v1, float v2) {
    float mx = fmaxf(v0, fmaxf(v1, v2));
    if (isinf(mx)) return NEGINF;
    return mx + __logf(__expf(v0 - mx) + __expf(v1 - mx) + __expf(v2 - mx));
}

// LDS-only barrier: ds ops ordered, global vector loads stay in flight.
#define STEP_BAR() do { \
    asm volatile("s_waitcnt lgkmcnt(0)" ::: "memory"); \
    __builtin_amdgcn_s_barrier(); \
    __builtin_amdgcn_sched_barrier(0); \
} while (0)

__global__ __launch_bounds__(256)
void scan_kernel(const float* __restrict__ lpl, const float* __restrict__ lpbk,
                 const int* __restrict__ hlens, const int* __restrict__ ys,
                 float* __restrict__ ast, float* __restrict__ bst)
{
    __shared__ float buf[2][412];
    __shared__ float ebs[Tn];            // blank emissions, preloaded (6.4 KB)
    __shared__ int   sh_olen, sh_hlen;

    const int b    = blockIdx.x & (Bn - 1);
    const int role = blockIdx.x >> 4;
    const int tid  = threadIdx.x;        // thread i owns states 2i, 2i+1

    if (tid == 0) {
        int o = 0;
        for (int u = 0; u < Un; u++) if (ys[b * Un + u] >= 0) o++;
        sh_olen = o;
        sh_hlen = hlens[b];
    }
    for (int idx = tid; idx < 412; idx += 256) {
        buf[0][idx] = NEGINF;
        buf[1][idx] = NEGINF;
    }
    const float* lpbb = lpbk + (size_t)b * Tn;
    for (int i = tid; i < Tn; i += 256) ebs[i] = lpbb[i];

    // allow flags (registers, loop-invariant). allow[u] = (ys[u-1]!=ys[u]),
    // valid for 1<=u<Un; clamped labels.
    auto allow_u = [&](int u) -> bool {
        if (u < 1 || u >= Un) return false;
        int y0 = ys[b * Un + u - 1]; if (y0 < 0) y0 = 0;
        int y1 = ys[b * Un + u];     if (y1 < 0) y1 = 0;
        return y0 != y1;
    };
    const bool a0allow = allow_u(tid - 1);   // odd state s0-1
    const bool a1allow = allow_u(tid);       // odd state s1
    const bool a2allow = allow_u(tid + 1);   // odd state s1+2
    const bool a3allow = allow_u(tid + 2);   // odd state s1+4 path
    __syncthreads();

    const float* lplb = lpl + (size_t)b * Tn * Un;
    const int s0 = 2 * tid, s1 = 2 * tid + 1;
    const bool v0ok = (s0 < Sn);         // tid <= 200
    const bool v1ok = (s1 < Sn);         // tid < 200
    const int  olen = sh_olen, hlen = sh_hlen;
    const int  ustar = olen - 1;

    if (role == 0) {
        // ------------------------- alpha -------------------------
        float* as = ast + (size_t)b * Tn;
        if (tid == 0) { buf[0][IDX(0)] = ebs[0]; buf[0][IDX(1)] = lplb[0]; }
        if (tid == ustar) as[0] = (tid == 0) ? lplb[0] : NEGINF;
        // prefetch first fused group's emissions (t=2): rows 2,3
        float pA0 = (tid >= 1 && tid <= Un) ? lplb[(size_t)2 * Un + tid - 1] : 0.f;
        float pA1 = (tid < Un) ? lplb[(size_t)2 * Un + tid] : 0.f;
        float pA2 = (tid < Un) ? lplb[(size_t)3 * Un + tid] : 0.f;
        float eo1 = (tid < Un) ? lplb[(size_t)1 * Un + tid] : 0.f;
        __syncthreads();

        // unfused step t=1: read buf[0], write buf[1]  (verbatim R14 ASTEP)
        {
            float eb = ebs[1];
            if (v0ok) {
                const float* cur = buf[0];
                float* nxt = buf[1];
                float c1 = cur[IDX(s0) - 1];
                float c2 = cur[IDX(s0)], c3 = cur[IDX(s1)];
                float nv0 = lse2f(c2, c1);
                if (!isinf(nv0)) nv0 += eb;
                nxt[IDX(s0)] = nv0;
                if (v1ok) {
                    float a1v2 = a1allow ? c1 : NEGINF;
                    float nv1 = lse3f(c3, c2, a1v2);
                    if (!isinf(nv1)) nv1 += eo1;
                    nxt[IDX(s1)] = nv1;
                    if (tid == ustar) as[1] = nv1;
                }
            }
            STEP_BAR();
        }
        // fused groups g=0..798: steps (t, t+1), t = 2+2g.
        // group g reads buf[1 ^ (g&1)], writes buf[g&1].
        for (int g = 0; g < 799; ++g) {
            const int t = 2 + 2 * g;
            // issue next group's emission loads (vector, vmcnt — survive bar)
            float nB0 = 0.f, nB1 = 0.f, nB2 = 0.f;
            if (g + 1 < 799) {
                const int tn = t + 2;
                nB0 = (tid >= 1 && tid <= Un) ? lplb[(size_t)tn * Un + tid - 1] : 0.f;
                nB1 = (tid < Un) ? lplb[(size_t)tn * Un + tid] : 0.f;
                nB2 = (tid < Un) ? lplb[(size_t)(tn + 1) * Un + tid] : 0.f;
            }
            float eb1 = ebs[t], eb2 = ebs[t + 1];
            const float* cur = buf[1 ^ (g & 1)];
            float* nxt = buf[g & 1];
            if (v0ok) {
                // 6 contiguous states: cur[2tid..2tid+5] = s0-4..s1
                float i1 = cur[2 * tid + 1], i2 = cur[2 * tid + 2],
                      i3 = cur[2 * tid + 3], i4 = cur[2 * tid + 4],
                      i5 = cur[2 * tid + 5];
                // L1 = step t (recomputed intermediates, bit-identical):
                float o_m1 = lse3f(i3, i2, a0allow ? i1 : NEGINF);   // state s0-1
                if (!isinf(o_m1)) o_m1 += pA0;
                float e_0 = lse2f(i4, i3);                            // state s0
                if (!isinf(e_0)) e_0 += eb1;
                float o_1 = lse3f(i5, i4, a1allow ? i3 : NEGINF);    // state s1
                if (!isinf(o_1)) o_1 += pA1;
                // L2 = step t+1 (finals):
                float f0 = lse2f(e_0, o_m1);
                if (!isinf(f0)) f0 += eb2;
                float f1 = lse3f(o_1, e_0, a1allow ? o_m1 : NEGINF);
                if (!isinf(f1)) f1 += pA2;
                nxt[IDX(s0)] = f0;
                if (v1ok) {
                    nxt[IDX(s1)] = f1;
                    if (tid == ustar) { as[t] = o_1; as[t + 1] = f1; }
                }
            }
            STEP_BAR();
            pA0 = nB0; pA1 = nB1; pA2 = nB2;
        }
    } else {
        // ------------------ beta + in-scan beta_prime ------------------
        float* bs = bst + (size_t)b * Tn;
        // classifier (verbatim R14)
        auto classify = [&](int T, float g0o, float h) -> float {
            float bp;
            if (T >= hlen)           bp = NEGINF;
            else if (T == hlen - 1)  bp = 0.f;            // tid==olen-1 here
            else if (isinf(g0o))     bp = h;
            else if (isinf(h))       bp = LSE_SUB_CONST_F;
            else {
                float sumlog = h - g0o;
                int k = (int)((__float_as_uint(fabsf(g0o)) >> 23) & 0xFF) - 127 - 53;
                if (k < -53) k = -53;
                bp = (sumlog > 709.7827f || sumlog < 0.69314718f * (float)k)
                     ? LSE_SUB_CONST_F : h;
            }
            return bp;
        };
        auto eload = [&](int row, int u) -> float {
            return (u < Un) ? lplb[(size_t)row * Un + u] : 0.f;
        };
        // groups g=0..799: steps (T, T-1), T = 1599-2g.
        // step T uses em row min(T+1,1599) (q); step T-1 uses row T (r).
        // g=0: both rows = 1599.
        float pq0 = eload(Tn - 1, tid);
        float pq1 = eload(Tn - 1, tid + 1);
        float pq2 = eload(Tn - 1, tid + 2);
        float pr0 = pq0, pr1 = pq1;
        __syncthreads();

        for (int g = 0; g < 800; ++g) {
            const int T = Tn - 1 - 2 * g;
            // next group's rows: T'-related rows T-1 (q), T-2 (r)
            float nq0 = 0.f, nq1 = 0.f, nq2 = 0.f, nr0 = 0.f, nr1 = 0.f;
            if (g + 1 < 800) {
                nq0 = eload(T - 1, tid);
                nq1 = eload(T - 1, tid + 1);
                nq2 = eload(T - 1, tid + 2);
                nr0 = eload(T - 2, tid);
                nr1 = eload(T - 2, tid + 1);
            }
            float ebT  = ebs[(T + 1 > Tn - 1) ? (Tn - 1) : (T + 1)];
            float ebT2 = ebs[T];
            const float* cur = buf[g & 1];
            float* nxt = buf[(g + 1) & 1];
            if (v0ok) {
                // 6 contiguous states: cur[2tid+4..2tid+9] = s0..s1+4
                float i0 = cur[2 * tid + 4], i1 = cur[2 * tid + 5],
                      i2 = cur[2 * tid + 6], i3 = cur[2 * tid + 7],
                      i4 = cur[2 * tid + 8], i5 = cur[2 * tid + 9];
                // ---- L1 = step T ----
                // state s0 (even):
                float E0 = lse2f(ebT + i0, pq0 + i1);
                // state s1 (odd, u=tid):
                float g0o = pq0 + i1;
                float g1o = ebT + i2;
                float g2o = a2allow ? (pq1 + i3) : NEGINF;
                float mh = fmaxf(g1o, g2o);
                float h = NEGINF;
                if (!isinf(mh))
                    h = mh + __logf(__expf(g1o - mh) + __expf(g2o - mh));
                float O1 = lse3f(g0o, g1o, g2o);
                // state s1+1 (even):
                float E2 = lse2f(ebT + i2, pq1 + i3);
                // state s1+2 (odd, u=tid+1):
                float O3 = lse3f(pq1 + i3, ebT + i4,
                                 a3allow ? (pq2 + i5) : NEGINF);
                if (T == hlen - 1) {
                    E0 = (s0 == 2 * olen || s0 == 2 * olen - 1) ? 0.f : NEGINF;
                    O1 = (s1 == 2 * olen || s1 == 2 * olen - 1) ? 0.f : NEGINF;
                    E2 = (s1 + 1 == 2 * olen || s1 + 1 == 2 * olen - 1) ? 0.f : NEGINF;
                    O3 = (s1 + 2 == 2 * olen || s1 + 2 == 2 * olen - 1) ? 0.f : NEGINF;
                }
                if (tid == ustar) bs[T] = classify(T, g0o, h);
                // ---- L2 = step T-1 (finals) ----
                float F0 = lse2f(ebT2 + E0, pr0 + O1);
                float G0o = pr0 + O1;
                float G1o = ebT2 + E2;
                float G2o = a2allow ? (pr1 + O3) : NEGINF;
                float MH = fmaxf(G1o, G2o);
                float H = NEGINF;
                if (!isinf(MH))
                    H = MH + __logf(__expf(G1o - MH) + __expf(G2o - MH));
                float F1 = lse3f(G0o, G1o, G2o);
                if (T - 1 == hlen - 1) {
                    F0 = (s0 == 2 * olen || s0 == 2 * olen - 1) ? 0.f : NEGINF;
                    F1 = (s1 == 2 * olen || s1 == 2 * olen - 1) ? 0.f : NEGINF;
                }
                nxt[IDX(s0)] = F0;
                if (v1ok) {
                    nxt[IDX(s1)] = F1;
                    if (tid == ustar) bs[T - 1] = classify(T - 1, G0o, H);
                }
            }
            STEP_BAR();
            pq0 = nq0; pq1 = nq1; pq2 = nq2; pr0 = nr0; pr1 = nr1;
        }
    }
}

// --------------------- K3: loss at u* only --------------------------------
#define TCH 8
#define TPC (Tn / TCH)

__global__ __launch_bounds__(64)
void loss_kernel(const int* __restrict__ hlens, const int* __restrict__ ys,
                 const float* __restrict__ ast, const float* __restrict__ bst,
                 float* __restrict__ lossb)
{
    const int b = blockIdx.x, tid = threadIdx.x;
    __shared__ float sm[TCH], ss[TCH];
    __shared__ int sh_olen;
    if (tid == 0) {
        int o = 0;
        for (int u = 0; u < Un; u++) if (ys[b * Un + u] >= 0) o++;
        sh_olen = o;
    }
    __syncthreads();
    const int hlen = hlens[b];
    const float risk_c = 0.1f / (float)hlen;
    if (tid < TCH) {
        float m = NEGINF, s = 0.f;
        const float* as = ast + (size_t)b * Tn;
        const float* bs = bst + (size_t)b * Tn;
        const int t0 = tid * TPC, t1 = t0 + TPC;
        for (int t = t0; t < t1; ++t) {
            float v = as[t] + bs[t] + (float)(t + 1) * risk_c;
            if (!isinf(v)) lse_merge_v(m, s, v);
        }
        sm[tid] = m; ss[tid] = s;
    }
    __syncthreads();
    if (tid == 0) {
        float M = NEGINF, S = 0.f;
        #pragma unroll
        for (int c = 0; c < TCH; ++c) lse_merge_ms(M, S, sm[c], ss[c]);
        float lf = (S == 0.f) ? NEGINF : M + __logf(S);
        if (hlen < sh_olen) lf = 0.f;
        lossb[b] = lf;
    }
}

// ---------------------------------------------------------------- K4 ------
__global__ void finalize_kernel(const float* __restrict__ lossb, float* __restrict__ out) {
    if (threadIdx.x == 0 && blockIdx.x == 0) {
        float ssum = 0.f;
        for (int i = 0; i < Bn; i++) ssum += lossb[i];
        out[0] = -ssum / (float)Bn;
    }
}

// ------------------------------------------------------------- launch -----
extern "C" void kernel_launch(void* const* d_in, const int* in_sizes, int n_in,
                              void* d_out, int out_size, void* d_ws, size_t ws_size,
                              hipStream_t stream) {
    const float* hs    = (const float*)d_in[0];
    const float* W     = (const float*)d_in[1];
    const float* bias  = (const float*)d_in[2];
    const int*   hlens = (const int*)d_in[3];
    const int*   ys    = (const int*)d_in[4];
    float* out = (float*)d_out;

    // ---- workspace (~57 MB) ----
    char* p = (char*)d_ws;
    float* lpl    = (float*)p;  p += (size_t)25600 * Un * 4;          // 20.48 MB
    float* lpbk   = (float*)p;  p += (size_t)25600 * 4;               // 0.10 MB
    unsigned short* hsb = (unsigned short*)p; p += (size_t)25600 * NE * 2;    // 26.2 MB
    unsigned short* Wb  = (unsigned short*)p; p += (size_t)OD * NE * 2;       // 2.1 MB
    unsigned short* Wgb = (unsigned short*)p; p += (size_t)Bn * NGC * NE * 2; // 4.2 MB
    float* Pm    = (float*)p;   p += (size_t)16 * 25600 * 4;          // 1.64 MB
    float* Ps    = (float*)p;   p += (size_t)16 * 25600 * 4;          // 1.64 MB
    float* lse   = (float*)p;   p += (size_t)25600 * 4;               // 0.10 MB
    float* biasg = (float*)p;   p += (size_t)Bn * NGC * 4;            // 16 KB
    float* ast   = (float*)p;   p += (size_t)Bn * Tn * 4;             // 0.10 MB
    float* bst   = (float*)p;   p += (size_t)Bn * Tn * 4;             // 0.10 MB
    float* lossb = (float*)p;   p += 256;

    hipLaunchKernelGGL(cast_hs_kernel, dim3(6400), dim3(256), 0, stream,
                       hs, hsb, 25600 * NE / 8);
    hipLaunchKernelGGL(cast_hs_kernel, dim3(512), dim3(256), 0, stream,
                       W, Wb, OD * NE / 8);
    hipLaunchKernelGGL(gather_kernel, dim3(Bn, NGC), dim3(64), 0, stream,
                       W, bias, ys, Wgb, biasg);
    hipLaunchKernelGGL(gemm_main_kernel, dim3(200, 16), dim3(256), 0, stream,
                       hsb, Wb, bias, Pm, Ps);
    hipLaunchKernelGGL(lse_reduce_kernel, dim3(100), dim3(256), 0, stream,
                       Pm, Ps, lse);
    hipLaunchKernelGGL(gemm_label_kernel, dim3(400, 2), dim3(256), 0, stream,
                       hsb, Wgb, biasg, lse, lpl, lpbk);
    hipLaunchKernelGGL(scan_kernel, dim3(2 * Bn), dim3(256), 0, stream,
                       lpl, lpbk, hlens, ys, ast, bst);
    hipLaunchKernelGGL(loss_kernel, dim3(Bn), dim3(64), 0, stream,
                       hlens, ys, ast, bst, lossb);
    hipLaunchKernelGGL(finalize_kernel, dim3(1), dim3(64), 0, stream, lossb, out);
}

// Round 7
// 1202.026 us; speedup vs baseline: 1.0931x; 1.0931x over previous
//
#include <hip/hip_runtime.h>
#include <math.h>

// BayesianCTC on MI355X — round 18.
// R16/R17 post-mortem: fusion regressed (983 vs 912); stall scaled with the
// NUMBER of emission loads per barrier round (3 loads ~1050cy, 5 loads
// ~2150cy), not with round trips; VALUBusy(active) only ~27%. Diagnosis: the
// `(tid<Un) ? load : 0.f` per-load ternaries serialize — each load sits in
// its own exec-masked region whose select forces a vmcnt drain (and/or
// regalloc sinks loads at VGPR=20). Fix: UNCONDITIONAL loads, addresses
// in-bounds by construction:
//  - lpl stride 200 -> 256 (+1 pad row); gemm_label zero-fills cols 201..255
//    (same 0.0f the ternary produced; edge lanes see identical inputs).
//  - unfused R14 scan structure (fusion disproven), ebs[] LDS preload,
//    depth-2 unconditional prefetch, redundant isinf-guards on +emission
//    dropped (-inf + finite = -inf, bit-identical).
// All state-update formulas verbatim R14 (lse ordering, classifier, resets).

#define Bn    16
#define Tn    1600
#define NE    512
#define OD    2048
#define Un    200
#define Sn    401
#define NLAB  201
#define NGC   256
#define LPS   256              // lpl row stride (floats)

#define NEGINF (-INFINITY)
#define LSE_SUB_CONST_F (-2000.4586715f)        // -2001 + log(e-1)

typedef short bf8_t  __attribute__((ext_vector_type(8)));
typedef float f32x4  __attribute__((ext_vector_type(4)));

__device__ __forceinline__ unsigned short f2bf(float x) {
    unsigned int u = __float_as_uint(x);
    unsigned int r = (u + 0x7FFFu + ((u >> 16) & 1u)) >> 16;  // RNE
    return (unsigned short)r;
}
__device__ __forceinline__ void lse_merge_v(float& M, float& S, float v) {
    if (v > M) { S = S * __expf(M - v) + 1.f; M = v; }
    else       { S += __expf(v - M); }
}
__device__ __forceinline__ void lse_merge_ms(float& M, float& S, float m2, float s2) {
    if (s2 > 0.f) {
        if (m2 > M) { S = S * __expf(M - m2) + s2; M = m2; }
        else        { S += s2 * __expf(m2 - M); }
    }
}

// ------------------------------------------------------------ casts -------
__global__ __launch_bounds__(256)
void cast_hs_kernel(const float* __restrict__ src, unsigned short* __restrict__ dst, int n8) {
    int i = blockIdx.x * 256 + threadIdx.x;
    if (i >= n8) return;
    const float4* s4 = (const float4*)(src + (size_t)i * 8);
    float4 a = s4[0], b = s4[1];
    uint4 o;
    o.x = f2bf(a.x) | ((unsigned)f2bf(a.y) << 16);
    o.y = f2bf(a.z) | ((unsigned)f2bf(a.w) << 16);
    o.z = f2bf(b.x) | ((unsigned)f2bf(b.y) << 16);
    o.w = f2bf(b.z) | ((unsigned)f2bf(b.w) << 16);
    *(uint4*)(dst + (size_t)i * 8) = o;
}

// --------------------------------------------------------- gather Wg ------
__global__ __launch_bounds__(64)
void gather_kernel(const float* __restrict__ W, const float* __restrict__ bias,
                   const int* __restrict__ ys, unsigned short* __restrict__ Wgb,
                   float* __restrict__ biasg)
{
    const int b = blockIdx.x, j = blockIdx.y, tid = threadIdx.x;
    int col = -1;
    if (j == 0) col = 0;
    else if (j <= Un) { int y = ys[b * Un + j - 1]; col = (y < 0) ? 0 : y; }
    unsigned short* dst = Wgb + ((size_t)b * NGC + j) * NE;
    if (col >= 0) {
        const float* srcc = W + (size_t)col * NE;
        #pragma unroll
        for (int it = 0; it < 8; ++it) dst[tid + it * 64] = f2bf(srcc[tid + it * 64]);
    } else {
        #pragma unroll
        for (int it = 0; it < 8; ++it) dst[tid + it * 64] = 0;
    }
    if (tid == 0) biasg[b * NGC + j] = (col >= 0) ? bias[col] : 0.f;
}

// ------------------------------------------------------- main MFMA GEMM ---
#define KCH  64
#define ASTR 72

__global__ __launch_bounds__(256, 2)
void gemm_main_kernel(const unsigned short* __restrict__ hsb,
                      const unsigned short* __restrict__ Wb,
                      const float* __restrict__ bias,
                      float* __restrict__ Pm, float* __restrict__ Ps)
{
    __shared__ union {
        struct { unsigned short A[128 * ASTR]; unsigned short B[128 * ASTR]; } t;
        struct { float m[128 * 33]; float s[128 * 33]; } r;
    } sh;
    const int tid  = threadIdx.x;
    const int lane = tid & 63, w = tid >> 6;
    const int mw = w & 1, nw = w >> 1;
    const int quad = lane >> 4, lc = lane & 15;
    const int row0 = blockIdx.x * 128;
    const int c0   = blockIdx.y * 128;

    f32x4 acc[4][4];
    #pragma unroll
    for (int mi = 0; mi < 4; ++mi)
        #pragma unroll
        for (int ni = 0; ni < 4; ++ni) acc[mi][ni] = (f32x4)0.f;

    for (int kc = 0; kc < NE / KCH; ++kc) {
        __syncthreads();
        #pragma unroll
        for (int i = 0; i < 4; ++i) {
            int idx = tid + i * 256;
            int r = idx >> 3, c8 = idx & 7;
            *(uint4*)&sh.t.A[r * ASTR + c8 * 8] =
                *(const uint4*)&hsb[(size_t)(row0 + r) * NE + kc * KCH + c8 * 8];
            *(uint4*)&sh.t.B[r * ASTR + c8 * 8] =
                *(const uint4*)&Wb[(size_t)(c0 + r) * NE + kc * KCH + c8 * 8];
        }
        __syncthreads();
        #pragma unroll
        for (int ks = 0; ks < 2; ++ks) {
            bf8_t af[4], bg[4];
            #pragma unroll
            for (int mi = 0; mi < 4; ++mi)
                af[mi] = *(const bf8_t*)&sh.t.A[(mw * 64 + mi * 16 + lc) * ASTR + ks * 32 + quad * 8];
            #pragma unroll
            for (int ni = 0; ni < 4; ++ni)
                bg[ni] = *(const bf8_t*)&sh.t.B[(nw * 64 + ni * 16 + lc) * ASTR + ks * 32 + quad * 8];
            #pragma unroll
            for (int mi = 0; mi < 4; ++mi)
                #pragma unroll
                for (int ni = 0; ni < 4; ++ni)
                    acc[mi][ni] = __builtin_amdgcn_mfma_f32_16x16x32_bf16(af[mi], bg[ni], acc[mi][ni], 0, 0, 0);
        }
    }
    __syncthreads();
    float bcol[4];
    #pragma unroll
    for (int ni = 0; ni < 4; ++ni) bcol[ni] = bias[c0 + nw * 64 + ni * 16 + lc];
    #pragma unroll
    for (int mi = 0; mi < 4; ++mi)
        #pragma unroll
        for (int r = 0; r < 4; ++r) {
            float M = NEGINF, S = 0.f;
            #pragma unroll
            for (int ni = 0; ni < 4; ++ni) lse_merge_v(M, S, acc[mi][ni][r] + bcol[ni]);
            int rl = mw * 64 + mi * 16 + quad * 4 + r;
            sh.r.m[rl * 33 + nw * 16 + lc] = M;
            sh.r.s[rl * 33 + nw * 16 + lc] = S;
        }
    __syncthreads();
    if (tid < 128) {
        float M = NEGINF, S = 0.f;
        #pragma unroll 4
        for (int j = 0; j < 32; ++j) lse_merge_ms(M, S, sh.r.m[tid * 33 + j], sh.r.s[tid * 33 + j]);
        Pm[(size_t)blockIdx.y * 25600 + row0 + tid] = M;
        Ps[(size_t)blockIdx.y * 25600 + row0 + tid] = S;
    }
}

// ------------------------------------------------------------ lse reduce --
__global__ __launch_bounds__(256)
void lse_reduce_kernel(const float* __restrict__ Pm, const float* __restrict__ Ps,
                       float* __restrict__ lse)
{
    int row = blockIdx.x * 256 + threadIdx.x;
    float M = NEGINF, S = 0.f;
    #pragma unroll 4
    for (int nt = 0; nt < 16; ++nt)
        lse_merge_ms(M, S, Pm[(size_t)nt * 25600 + row], Ps[(size_t)nt * 25600 + row]);
    lse[row] = M + logf(S);
}

// ------------------------------------------------------- label MFMA GEMM --
// Output split: lpbk[row] = blank col; lpl[row][u] (stride LPS=256) = label
// u = col-1 for col in 1..200; cols 201..255 zero-filled (scan reads them
// unconditionally; 0.0f matches the old ternary's value).
__global__ __launch_bounds__(256, 2)
void gemm_label_kernel(const unsigned short* __restrict__ hsb,
                       const unsigned short* __restrict__ Wgb,
                       const float* __restrict__ biasg, const float* __restrict__ lse,
                       float* __restrict__ lpl, float* __restrict__ lpbk)
{
    __shared__ unsigned short shA[64 * ASTR];
    __shared__ unsigned short shB[128 * ASTR];
    const int tid  = threadIdx.x;
    const int lane = tid & 63, w = tid >> 6;
    const int mw = w & 1, nw = w >> 1;
    const int quad = lane >> 4, lc = lane & 15;
    const int b  = blockIdx.x / 25, mt = blockIdx.x % 25;
    const int r0 = b * Tn + mt * 64;
    const int c0 = blockIdx.y * 128;

    f32x4 acc[2][4];
    #pragma unroll
    for (int mi = 0; mi < 2; ++mi)
        #pragma unroll
        for (int ni = 0; ni < 4; ++ni) acc[mi][ni] = (f32x4)0.f;

    const unsigned short* Wgbb = Wgb + (size_t)b * NGC * NE;
    for (int kc = 0; kc < NE / KCH; ++kc) {
        __syncthreads();
        #pragma unroll
        for (int i = 0; i < 2; ++i) {
            int idx = tid + i * 256;
            int r = idx >> 3, c8 = idx & 7;
            *(uint4*)&shA[r * ASTR + c8 * 8] =
                *(const uint4*)&hsb[(size_t)(r0 + r) * NE + kc * KCH + c8 * 8];
        }
        #pragma unroll
        for (int i = 0; i < 4; ++i) {
            int idx = tid + i * 256;
            int r = idx >> 3, c8 = idx & 7;
            *(uint4*)&shB[r * ASTR + c8 * 8] =
                *(const uint4*)&Wgbb[(size_t)(c0 + r) * NE + kc * KCH + c8 * 8];
        }
        __syncthreads();
        #pragma unroll
        for (int ks = 0; ks < 2; ++ks) {
            bf8_t af[2], bg[4];
            #pragma unroll
            for (int mi = 0; mi < 2; ++mi)
                af[mi] = *(const bf8_t*)&shA[(mw * 32 + mi * 16 + lc) * ASTR + ks * 32 + quad * 8];
            #pragma unroll
            for (int ni = 0; ni < 4; ++ni)
                bg[ni] = *(const bf8_t*)&shB[(nw * 64 + ni * 16 + lc) * ASTR + ks * 32 + quad * 8];
            #pragma unroll
            for (int mi = 0; mi < 2; ++mi)
                #pragma unroll
                for (int ni = 0; ni < 4; ++ni)
                    acc[mi][ni] = __builtin_amdgcn_mfma_f32_16x16x32_bf16(af[mi], bg[ni], acc[mi][ni], 0, 0, 0);
        }
    }
    #pragma unroll
    for (int mi = 0; mi < 2; ++mi)
        #pragma unroll
        for (int r = 0; r < 4; ++r) {
            int row = r0 + mw * 32 + mi * 16 + quad * 4 + r;
            float lsv = lse[row];
            #pragma unroll
            for (int ni = 0; ni < 4; ++ni) {
                int col = c0 + nw * 64 + ni * 16 + lc;
                float v = acc[mi][ni][r] + biasg[b * NGC + col] - lsv;
                if (col == 0)          lpbk[row] = v;
                else if (col < NLAB)   lpl[(size_t)row * LPS + (col - 1)] = v;
                else                   lpl[(size_t)row * LPS + (col - 1)] = 0.f;
            }
        }
}

// ------------------- K2: LDS ping-pong scan, light barrier ----------------
#define IDX(s) ((s) + 2)          // buf index for state s; pads [0,1],[403..407]

__device__ __forceinline__ float lse2f(float a, float b) {
    float mx = fmaxf(a, b);
    if (isinf(mx)) return NEGINF;
    return mx + __logf(__expf(a - mx) + __expf(b - mx));
}
__device__ __forceinline__ float lse3f(float v0, float v1, float v2) {
    float mx = fmaxf(v0, fmaxf(v1, v2));
    if (isinf(mx)) return NEGINF;
    return mx + __logf(__expf(v0 - mx) + __expf(v1 - mx) + __expf(v2 - mx));
}

// LDS-only barrier: ds ops ordered, global vector loads stay in flight.
#define STEP_BAR() do { \
    asm volatile("s_waitcnt lgkmcnt(0)" ::: "memory"); \
    __builtin_amdgcn_s_barrier(); \
    __builtin_amdgcn_sched_barrier(0); \
} while (0)

__global__ __launch_bounds__(256)
void scan_kernel(const float* __restrict__ lpl, const float* __restrict__ lpbk,
                 const int* __restrict__ hlens, const int* __restrict__ ys,
                 float* __restrict__ ast, float* __restrict__ bst)
{
    __shared__ float buf[2][408];
    __shared__ float ebs[Tn];            // blank emissions, preloaded (6.4 KB)
    __shared__ int   sh_olen, sh_hlen;

    const int b    = blockIdx.x & (Bn - 1);
    const int role = blockIdx.x >> 4;
    const int tid  = threadIdx.x;        // thread i owns states 2i, 2i+1

    if (tid == 0) {
        int o = 0;
        for (int u = 0; u < Un; u++) if (ys[b * Un + u] >= 0) o++;
        sh_olen = o;
        sh_hlen = hlens[b];
    }
    for (int idx = tid; idx < 408; idx += 256) {
        buf[0][idx] = NEGINF;
        buf[1][idx] = NEGINF;
    }
    const float* lpbb = lpbk + (size_t)b * Tn;
    for (int i = tid; i < Tn; i += 256) ebs[i] = lpbb[i];

    // allow flags in registers (loop-invariant)
    bool a1allow = false;                // allow for odd state s1 (u = tid)
    if (tid >= 1 && tid < Un) {
        int y0 = ys[b * Un + tid - 1]; if (y0 < 0) y0 = 0;
        int y1 = ys[b * Un + tid];     if (y1 < 0) y1 = 0;
        a1allow = (y0 != y1);
    }
    bool a2allow = false;                // allow for odd state s1+2 (u = tid+1)
    if (tid + 1 >= 1 && tid + 1 < Un) {
        int y0 = ys[b * Un + tid];     if (y0 < 0) y0 = 0;
        int y1 = ys[b * Un + tid + 1]; if (y1 < 0) y1 = 0;
        a2allow = (y0 != y1);
    }
    __syncthreads();

    const float* lplb = lpl + (size_t)b * Tn * LPS;
    const int s0 = 2 * tid, s1 = 2 * tid + 1;
    const bool v0ok = (s0 < Sn);         // tid <= 200
    const bool v1ok = (s1 < Sn);         // tid < 200
    const int  olen = sh_olen, hlen = sh_hlen;
    const int  ustar = olen - 1;

    if (role == 0) {
        // ------------------------- alpha -------------------------
        float* as = ast + (size_t)b * Tn;
        if (tid == 0) { buf[0][IDX(0)] = ebs[0]; buf[0][IDX(1)] = lplb[0]; }
        if (tid == ustar) as[0] = (tid == 0) ? lplb[0] : NEGINF;
        __syncthreads();

        // Unconditional loads: lpl stride 256 makes row*LPS + tid in-bounds
        // for all tid < 256; lanes >= Un read zero-filled columns (dead).
        #define ASTEP(T, EO) do { \
            const float* cur = buf[((T) - 1) & 1]; \
            float* nxt = buf[(T) & 1]; \
            if (v0ok) { \
                float c1 = cur[IDX(s0) - 1]; \
                float c2 = cur[IDX(s0)], c3 = cur[IDX(s1)]; \
                float nv0 = lse2f(c2, c1) + ebs[T]; \
                nxt[IDX(s0)] = nv0; \
                if (v1ok) { \
                    float a1v2 = a1allow ? c1 : NEGINF; \
                    float nv1 = lse3f(c3, c2, a1v2) + (EO); \
                    nxt[IDX(s1)] = nv1; \
                    if (tid == ustar) as[T] = nv1; \
                } \
            } \
            STEP_BAR(); \
        } while (0)

        // depth-2 prefetch: sets A,B hold emission rows t, t+1
        float eoA = lplb[(size_t)1 * LPS + tid];
        float eoB = lplb[(size_t)2 * LPS + tid];
        for (int t = 1; t < Tn; t += 2) {
            int rA = t + 2; if (rA > Tn - 1) rA = Tn - 1;
            float nA = lplb[(size_t)rA * LPS + tid];
            ASTEP(t, eoA); eoA = nA;
            if (t + 1 < Tn) {
                int rB = t + 3; if (rB > Tn - 1) rB = Tn - 1;
                float nB = lplb[(size_t)rB * LPS + tid];
                ASTEP(t + 1, eoB); eoB = nB;
            }
        }
        #undef ASTEP
    } else {
        // ------------------ beta + in-scan beta_prime ------------------
        float* bs = bst + (size_t)b * Tn;

        #define BSTEP(T, E0, E1) do { \
            const int it = (Tn - 1 - (T)) & 1; \
            const float* cur = buf[it]; \
            float* nxt = buf[it ^ 1]; \
            float eb = ebs[((T) + 1 > Tn - 1) ? (Tn - 1) : ((T) + 1)]; \
            if (v0ok) { \
                float c0 = cur[IDX(s0)],     c1 = cur[IDX(s0) + 1]; \
                float c2 = cur[IDX(s0) + 2], c3 = cur[IDX(s0) + 3]; \
                float g0e = eb + c0; \
                float g1e = (E0) + c1; \
                float nv0 = lse2f(g0e, g1e); \
                float g0o = (E0) + c1; \
                float g1o = eb + c2; \
                float g2o = a2allow ? ((E1) + c3) : NEGINF; \
                float mh = fmaxf(g1o, g2o); \
                float h = NEGINF; \
                if (!isinf(mh)) \
                    h = mh + __logf(__expf(g1o - mh) + __expf(g2o - mh)); \
                float nv1 = v1ok ? lse3f(g0o, g1o, g2o) : NEGINF; \
                if ((T) == hlen - 1) { \
                    nv0 = (s0 == 2 * olen || s0 == 2 * olen - 1) ? 0.f : NEGINF; \
                    nv1 = (s1 == 2 * olen || s1 == 2 * olen - 1) ? 0.f : NEGINF; \
                } \
                nxt[IDX(s0)] = nv0; \
                if (v1ok) { \
                    nxt[IDX(s1)] = nv1; \
                    if (tid == ustar) { \
                        float bp; \
                        if ((T) >= hlen)          bp = NEGINF; \
                        else if ((T) == hlen - 1) bp = 0.f; /* tid==olen-1 */ \
                        else if (isinf(g0o))      bp = h; \
                        else if (isinf(h))        bp = LSE_SUB_CONST_F; \
                        else { \
                            float sumlog = h - g0o; \
                            int k = (int)((__float_as_uint(fabsf(g0o)) >> 23) & 0xFF) - 127 - 53; \
                            if (k < -53) k = -53; \
                            bp = (sumlog > 709.7827f || sumlog < 0.69314718f * (float)k) \
                                 ? LSE_SUB_CONST_F : h; \
                        } \
                        bs[T] = bp; \
                    } \
                } \
            } \
            STEP_BAR(); \
        } while (0)

        // step T uses emission row min(T+1, Tn-1). Unconditional loads.
        // prologue: steps 1599,1598 both use row 1599.
        float e0A = lplb[(size_t)(Tn - 1) * LPS + tid];
        float e1A = lplb[(size_t)(Tn - 1) * LPS + tid + 1];
        float e0B = e0A, e1B = e1A;
        for (int t = Tn - 1; t > 0; t -= 2) {   // 800 iters, steps t, t-1
            int rA = t - 1;                      // row for step t-2
            float n0A = lplb[(size_t)rA * LPS + tid];
            float n1A = lplb[(size_t)rA * LPS + tid + 1];
            BSTEP(t, e0A, e1A);
            e0A = n0A; e1A = n1A;

            int rB = t - 2; if (rB < 0) rB = 0;  // row for step t-3
            float n0B = lplb[(size_t)rB * LPS + tid];
            float n1B = lplb[(size_t)rB * LPS + tid + 1];
            BSTEP(t - 1, e0B, e1B);
            e0B = n0B; e1B = n1B;
        }
        #undef BSTEP
    }
}

// --------------------- K3: loss at u* only --------------------------------
#define TCH 8
#define TPC (Tn / TCH)

__global__ __launch_bounds__(64)
void loss_kernel(const int* __restrict__ hlens, const int* __restrict__ ys,
                 const float* __restrict__ ast, const float* __restrict__ bst,
                 float* __restrict__ lossb)
{
    const int b = blockIdx.x, tid = threadIdx.x;
    __shared__ float sm[TCH], ss[TCH];
    __shared__ int sh_olen;
    if (tid == 0) {
        int o = 0;
        for (int u = 0; u < Un; u++) if (ys[b * Un + u] >= 0) o++;
        sh_olen = o;
    }
    __syncthreads();
    const int hlen = hlens[b];
    const float risk_c = 0.1f / (float)hlen;
    if (tid < TCH) {
        float m = NEGINF, s = 0.f;
        const float* as = ast + (size_t)b * Tn;
        const float* bs = bst + (size_t)b * Tn;
        const int t0 = tid * TPC, t1 = t0 + TPC;
        for (int t = t0; t < t1; ++t) {
            float v = as[t] + bs[t] + (float)(t + 1) * risk_c;
            if (!isinf(v)) lse_merge_v(m, s, v);
        }
        sm[tid] = m; ss[tid] = s;
    }
    __syncthreads();
    if (tid == 0) {
        float M = NEGINF, S = 0.f;
        #pragma unroll
        for (int c = 0; c < TCH; ++c) lse_merge_ms(M, S, sm[c], ss[c]);
        float lf = (S == 0.f) ? NEGINF : M + __logf(S);
        if (hlen < sh_olen) lf = 0.f;
        lossb[b] = lf;
    }
}

// ---------------------------------------------------------------- K4 ------
__global__ void finalize_kernel(const float* __restrict__ lossb, float* __restrict__ out) {
    if (threadIdx.x == 0 && blockIdx.x == 0) {
        float ssum = 0.f;
        for (int i = 0; i < Bn; i++) ssum += lossb[i];
        out[0] = -ssum / (float)Bn;
    }
}

// ------------------------------------------------------------- launch -----
extern "C" void kernel_launch(void* const* d_in, const int* in_sizes, int n_in,
                              void* d_out, int out_size, void* d_ws, size_t ws_size,
                              hipStream_t stream) {
    const float* hs    = (const float*)d_in[0];
    const float* W     = (const float*)d_in[1];
    const float* bias  = (const float*)d_in[2];
    const int*   hlens = (const int*)d_in[3];
    const int*   ys    = (const int*)d_in[4];
    float* out = (float*)d_out;

    // ---- workspace (~63 MB) ----
    char* p = (char*)d_ws;
    float* lpl    = (float*)p;  p += (size_t)25601 * LPS * 4;         // 26.2 MB (stride 256, +1 pad row)
    float* lpbk   = (float*)p;  p += (size_t)25600 * 4;               // 0.10 MB
    unsigned short* hsb = (unsigned short*)p; p += (size_t)25600 * NE * 2;    // 26.2 MB
    unsigned short* Wb  = (unsigned short*)p; p += (size_t)OD * NE * 2;       // 2.1 MB
    unsigned short* Wgb = (unsigned short*)p; p += (size_t)Bn * NGC * NE * 2; // 4.2 MB
    float* Pm    = (float*)p;   p += (size_t)16 * 25600 * 4;          // 1.64 MB
    float* Ps    = (float*)p;   p += (size_t)16 * 25600 * 4;          // 1.64 MB
    float* lse   = (float*)p;   p += (size_t)25600 * 4;               // 0.10 MB
    float* biasg = (float*)p;   p += (size_t)Bn * NGC * 4;            // 16 KB
    float* ast   = (float*)p;   p += (size_t)Bn * Tn * 4;             // 0.10 MB
    float* bst   = (float*)p;   p += (size_t)Bn * Tn * 4;             // 0.10 MB
    float* lossb = (float*)p;   p += 256;

    hipLaunchKernelGGL(cast_hs_kernel, dim3(6400), dim3(256), 0, stream,
                       hs, hsb, 25600 * NE / 8);
    hipLaunchKernelGGL(cast_hs_kernel, dim3(512), dim3(256), 0, stream,
                       W, Wb, OD * NE / 8);
    hipLaunchKernelGGL(gather_kernel, dim3(Bn, NGC), dim3(64), 0, stream,
                       W, bias, ys, Wgb, biasg);
    hipLaunchKernelGGL(gemm_main_kernel, dim3(200, 16), dim3(256), 0, stream,
                       hsb, Wb, bias, Pm, Ps);
    hipLaunchKernelGGL(lse_reduce_kernel, dim3(100), dim3(256), 0, stream,
                       Pm, Ps, lse);
    hipLaunchKernelGGL(gemm_label_kernel, dim3(400, 2), dim3(256), 0, stream,
                       hsb, Wgb, biasg, lse, lpl, lpbk);
    hipLaunchKernelGGL(scan_kernel, dim3(2 * Bn), dim3(256), 0, stream,
                       lpl, lpbk, hlens, ys, ast, bst);
    hipLaunchKernelGGL(loss_kernel, dim3(Bn), dim3(64), 0, stream,
                       hlens, ys, ast, bst, lossb);
    hipLaunchKernelGGL(finalize_kernel, dim3(1), dim3(64), 0, stream, lossb, out);
}